// Round 11
// baseline (1491.624 us; speedup 1.0000x reference)
//
#include <hip/hip_runtime.h>
#include <stdint.h>

// Problem constants (n=1, c=32, h=w=128, p=3)
#define NPT    16384        // points (h*w)
#define KD     288          // c*p*p
#define KE     576          // per-point row: [hi(288) | lo(288)] f16
#define NWIN   9            // 9 merged K-windows of 32 (hi+lo staged together)

typedef _Float16 f16;
typedef __attribute__((ext_vector_type(8))) _Float16 half8;
typedef __attribute__((ext_vector_type(4))) float floatx4;

// -------- patch extraction + fp32->2xf16 split + fused norms/init ------------
__global__ void extract_split_kernel(const float* __restrict__ src,
                                     const float* __restrict__ tgt,
                                     f16* __restrict__ Aext,
                                     f16* __restrict__ Bext,
                                     float* __restrict__ rq,
                                     float* __restrict__ rp,
                                     unsigned long long* __restrict__ best) {
  int tid = blockIdx.x * 256 + threadIdx.x;   // 16384*32 threads
  int point = tid >> 5;
  int c = tid & 31;
  int y = point >> 7, x = point & 127;
  f16* arow = Aext + (size_t)point * KE;
  f16* brow = Bext + (size_t)point * KE;
  double sq = 0.0, sp = 0.0;
#pragma unroll
  for (int dy = 0; dy < 3; ++dy) {
    int yy = y + dy - 1; yy = yy < 0 ? 0 : (yy > 127 ? 127 : yy);
#pragma unroll
    for (int dx = 0; dx < 3; ++dx) {
      int xx = x + dx - 1; xx = xx < 0 ? 0 : (xx > 127 ? 127 : xx);
      int k = c * 9 + dy * 3 + dx;
      int m = (c << 14) + (yy << 7) + xx;
      float v = src[m];
      sq += (double)v * (double)v;
      f16 h = (f16)v;
      arow[k] = h; arow[KD + k] = (f16)(v - (float)h);
      v = tgt[m];
      sp += (double)v * (double)v;
      h = (f16)v;
      brow[k] = h; brow[KD + k] = (f16)(v - (float)h);
    }
  }
  // width-32 reduction over the 32 channels of this point
#pragma unroll
  for (int s = 1; s < 32; s <<= 1) {
    sq += __shfl_xor(sq, s, 32);
    sp += __shfl_xor(sp, s, 32);
  }
  if (c == 0) {
    rq[point] = (float)sq;
    rp[point] = (float)sp;
    best[point] = 0xFFFFFFFFFFFFFFFFULL;
  }
}

// --- MFMA GEMM: register-relay pipeline (global->VGPR->ds_write) -------------
// LDS tile: 128 rows x 64 halves (8 slots of 16 B), single buffer (32 KB).
// Logical slice s of row r lives at phys slot (s ^ (r & 7)):
//   s in [0,4): hi window octet s;  s in [4,8): lo octet s-4.
// Pipeline per window:
//   barrier(a); ds_write staged regs (vmcnt wait ~0: loads are a window old);
//   barrier(b) (lgkm-only); issue loads for kw+1 (fly across compute);
//   compute(kw).
// Unlike global_load_lds (shared dest -> forced vmcnt(0) drain at the
// barrier, the m97-plateau stall we measured through rounds 7-10), plain
// global loads target private VGPRs: no outstanding vm ops at barrier (b),
// and at barrier (a) the in-flight loads are ~2000 cyc old. 16x16x32
// fragment path (measured 0 bank conflicts). No min-waves bound (round 6:
// forced bound spilled the accumulator; round 10's (256,4) caused a small
// spill). ~150 regs -> 3 blocks/CU.
__global__ __launch_bounds__(256)
void gemm_argmin_kernel(const f16* __restrict__ A, const f16* __restrict__ B,
                        const float* __restrict__ rq,
                        unsigned long long* __restrict__ best) {
  __shared__ f16 Ash[128 * 64];   // 16 KB
  __shared__ f16 Bsh[128 * 64];   // 16 KB

  const int nBase = blockIdx.x * 128;
  const int mBase = blockIdx.y * 128;
  const f16* Ab = A + (size_t)mBase * KE;   // block-uniform -> SGPR pair
  const f16* Bb = B + (size_t)nBase * KE;
  const int t = threadIdx.x;
  const int w = t >> 6;           // wave 0..3
  const int l = t & 63;

  // ---- staging decode: per issue, 64 lanes cover 8 rows x 8 phys slots ----
  const int lr = l >> 3;                 // row within 8-row issue group
  const int lt = l & 7;                  // phys 16B slot
  const int sl = lt ^ (lr & 7);          // logical slice this lane carries
  const int sColOff = (sl < 4) ? sl * 8 : KD + (sl & 3) * 8;  // + kw*32/window
  int rowHalf[4];                        // identical for A and B
  uint32_t ldsOff[4];                    // LDS half-index of this lane's 16 B
#pragma unroll
  for (int ig = 0; ig < 4; ++ig) {
    rowHalf[ig] = (w * 32 + ig * 8 + lr) * KE + sColOff;
    ldsOff[ig] = (w * 32 + ig * 8 + lr) * 64 + lt * 8;
  }

  // ---- fragment decode (16x16x32) ----
  const int m16 = l & 15;
  const int q   = l >> 4;                // k-quad
  const int pHi = q ^ (m16 & 7);         // phys slot of hi octet q
  const int pLo = pHi ^ 4;               // phys slot of lo octet q
  const int wRow = (w & 1) * 64;
  const int wCol = (w >> 1) * 64;
  const int aHiOff = m16 * 64 + pHi * 8; // + (wRow + i*16)*64
  const int aLoOff = m16 * 64 + pLo * 8;

  floatx4 acc[4][4] = {};

  uint4 sa[4], sb[4];                    // staged 16 B chunks (32 VGPRs)
#pragma unroll
  for (int ig = 0; ig < 4; ++ig) {
    sa[ig] = *(const uint4*)(Ab + rowHalf[ig]);
    sb[ig] = *(const uint4*)(Bb + rowHalf[ig]);
  }

#pragma unroll
  for (int kw = 0; kw < NWIN; ++kw) {
    __syncthreads();                     // (a) previous window's reads done
#pragma unroll
    for (int ig = 0; ig < 4; ++ig) {
      *(uint4*)&Ash[ldsOff[ig]] = sa[ig];
      *(uint4*)&Bsh[ldsOff[ig]] = sb[ig];
    }
    __syncthreads();                     // (b) lgkm-only drain of ds_writes

    if (kw + 1 < NWIN) {
#pragma unroll
      for (int ig = 0; ig < 4; ++ig) {
        sa[ig] = *(const uint4*)(Ab + rowHalf[ig] + (kw + 1) * 32);
        sb[ig] = *(const uint4*)(Bb + rowHalf[ig] + (kw + 1) * 32);
      }
    }

    // phase 1: hi.hi — ah, bh resident
    half8 ah[4], bh[4];
#pragma unroll
    for (int i = 0; i < 4; ++i)
      ah[i] = *(const half8*)&Ash[(wRow + i * 16) * 64 + aHiOff];
#pragma unroll
    for (int j = 0; j < 4; ++j)
      bh[j] = *(const half8*)&Bsh[(wCol + j * 16) * 64 + aHiOff];
#pragma unroll
    for (int i = 0; i < 4; ++i)
#pragma unroll
      for (int j = 0; j < 4; ++j)
        acc[i][j] = __builtin_amdgcn_mfma_f32_16x16x32_f16(ah[i], bh[j], acc[i][j], 0, 0, 0);

    // phase 2: hi.lo — stream bl one tile at a time
#pragma unroll
    for (int j = 0; j < 4; ++j) {
      half8 bl = *(const half8*)&Bsh[(wCol + j * 16) * 64 + aLoOff];
#pragma unroll
      for (int i = 0; i < 4; ++i)
        acc[i][j] = __builtin_amdgcn_mfma_f32_16x16x32_f16(ah[i], bl, acc[i][j], 0, 0, 0);
    }
    // phase 3: lo.hi — ah dead; stream al one tile at a time
#pragma unroll
    for (int i = 0; i < 4; ++i) {
      half8 al = *(const half8*)&Ash[(wRow + i * 16) * 64 + aLoOff];
#pragma unroll
      for (int j = 0; j < 4; ++j)
        acc[i][j] = __builtin_amdgcn_mfma_f32_16x16x32_f16(al, bh[j], acc[i][j], 0, 0, 0);
    }
  }

  // ---- epilogue: f = rq[col] - 2*dot, packed argmin ----
  // C/D layout (16x16): col = lane&15, row = (lane>>4)*4 + reg
  const int colBase = nBase + wCol + m16;
  float rqv[4];
#pragma unroll
  for (int j = 0; j < 4; ++j) rqv[j] = rq[colBase + j * 16];

#pragma unroll
  for (int i = 0; i < 4; ++i) {
    const int rowB = mBase + wRow + i * 16 + q * 4;
#pragma unroll
    for (int r = 0; r < 4; ++r) {
      unsigned long long pk = 0xFFFFFFFFFFFFFFFFULL;
#pragma unroll
      for (int j = 0; j < 4; ++j) {
        float f = fmaf(-2.0f, acc[i][j][r], rqv[j]);
        unsigned int bits = __float_as_uint(f);
        unsigned int key = (bits & 0x80000000u) ? ~bits : (bits | 0x80000000u);
        unsigned long long cand =
            ((unsigned long long)key << 32) | (unsigned)(colBase + j * 16);
        pk = pk < cand ? pk : cand;
      }
#pragma unroll
      for (int sft = 1; sft < 16; sft <<= 1) {
        unsigned long long o = __shfl_xor(pk, sft, 16);
        pk = pk < o ? pk : o;
      }
      if (m16 == 0) atomicMin(best + rowB + r, pk);
    }
  }
}

// ---------------------------- finalize ---------------------------------------
__global__ void finalize_kernel(const unsigned long long* __restrict__ best,
                                const float* __restrict__ rp,
                                float* __restrict__ out) {
  int i = blockIdx.x * 256 + threadIdx.x;
  if (i >= NPT) return;
  unsigned long long v = best[i];
  unsigned int col = (unsigned int)(v & 0xFFFFFFFFu);
  unsigned int key = (unsigned int)(v >> 32);
  unsigned int bits = (key & 0x80000000u) ? (key & 0x7FFFFFFFu) : ~key;
  float fmin = __uint_as_float(bits);
  out[i]           = (float)(col >> 7);   // idy
  out[NPT + i]     = (float)(col & 127);  // idx
  out[2 * NPT + i] = rp[i] + fmin;        // nnd
}

extern "C" void kernel_launch(void* const* d_in, const int* in_sizes, int n_in,
                              void* d_out, int out_size, void* d_ws, size_t ws_size,
                              hipStream_t stream) {
  const float* src = (const float*)d_in[0];  // source_map (1,32,128,128)
  const float* tgt = (const float*)d_in[1];  // target_map (1,32,128,128)
  float* out = (float*)d_out;

  // workspace layout (bytes):
  //   Aext: [0, 18874368)        16384 x 576 f16 (point-major [hi|lo])
  //   Bext: [18874368, 37748736)
  //   rq  : [37748736, 37814272) 16384 fp32 (target-side norms for the f-term)
  //   rp  : [37814272, 37879808)
  //   best: [37879808, 38010880) 16384 u64 packed (key<<32)|col
  char* ws = (char*)d_ws;
  f16* Aext = (f16*)(ws);
  f16* Bext = (f16*)(ws + 18874368);
  float* rq = (float*)(ws + 37748736);
  float* rp = (float*)(ws + 37814272);
  unsigned long long* best = (unsigned long long*)(ws + 37879808);

  extract_split_kernel<<<(NPT * 32) / 256, 256, 0, stream>>>(src, tgt, Aext, Bext,
                                                             rq, rp, best);
  {
    dim3 grid(128, 128);
    gemm_argmin_kernel<<<grid, 256, 0, stream>>>(Aext, Bext, rq, best);
  }
  finalize_kernel<<<NPT / 256, 256, 0, stream>>>(best, rp, out);
}

// Round 12
// 574.209 us; speedup vs baseline: 2.5977x; 2.5977x over previous
//
#include <hip/hip_runtime.h>
#include <stdint.h>

// Problem constants (n=1, c=32, h=w=128, p=3)
#define NPT    16384        // points (h*w)
#define KD     288          // c*p*p
#define KE     576          // per-point row: [hi(288) | lo(288)] f16
#define NWIN   9            // 9 merged K-windows of 32 (hi+lo staged together)

typedef _Float16 f16;
typedef __attribute__((ext_vector_type(8))) _Float16 half8;
typedef __attribute__((ext_vector_type(4))) float floatx4;

#define AS1(p) ((const __attribute__((address_space(1))) uint32_t*)(p))
#define AS3(p) ((__attribute__((address_space(3))) uint32_t*)(p))

// -------- patch extraction + fp32->2xf16 split + fused norms/init ------------
// Block = 32 consecutive points, 256 threads. Lanes sweep points -> 128 B
// contiguous global reads; output staged in LDS and stored as exactly
// 9 coalesced uint4 chunks per thread (32*576 halves = 2304 chunks = 9*256).
__global__ __launch_bounds__(256)
void extract_split_kernel(const float* __restrict__ src,
                          const float* __restrict__ tgt,
                          f16* __restrict__ Aext,
                          f16* __restrict__ Bext,
                          float* __restrict__ rq,
                          float* __restrict__ rp,
                          unsigned long long* __restrict__ best) {
  __shared__ f16 bufA[32 * KE];       // 36 KB
  __shared__ f16 bufB[32 * KE];       // 36 KB
  __shared__ double prtA[8][32];
  __shared__ double prtB[8][32];

  const int tid = threadIdx.x;
  const int p  = tid & 31;            // local point
  const int cg = tid >> 5;            // channel group 0..7
  const int point = blockIdx.x * 32 + p;
  const int y = point >> 7, x = point & 127;

  double sq = 0.0, sp_ = 0.0;
#pragma unroll
  for (int cc = 0; cc < 4; ++cc) {
    const int c = cg * 4 + cc;
#pragma unroll
    for (int dy = 0; dy < 3; ++dy) {
      int yy = y + dy - 1; yy = yy < 0 ? 0 : (yy > 127 ? 127 : yy);
#pragma unroll
      for (int dx = 0; dx < 3; ++dx) {
        int xx = x + dx - 1; xx = xx < 0 ? 0 : (xx > 127 ? 127 : xx);
        const int k = c * 9 + dy * 3 + dx;
        const int m = (c << 14) + (yy << 7) + xx;
        float v = src[m];
        sq += (double)v * (double)v;
        f16 h = (f16)v;
        bufA[p * KE + k] = h;
        bufA[p * KE + KD + k] = (f16)(v - (float)h);
        v = tgt[m];
        sp_ += (double)v * (double)v;
        h = (f16)v;
        bufB[p * KE + k] = h;
        bufB[p * KE + KD + k] = (f16)(v - (float)h);
      }
    }
  }
  prtA[cg][p] = sq;
  prtB[cg][p] = sp_;
  __syncthreads();

  if (tid < 32) {
    double s = 0.0;
#pragma unroll
    for (int g = 0; g < 8; ++g) s += prtA[g][tid];
    rq[blockIdx.x * 32 + tid] = (float)s;
    best[blockIdx.x * 32 + tid] = 0xFFFFFFFFFFFFFFFFULL;
  } else if (tid < 64) {
    double s = 0.0;
#pragma unroll
    for (int g = 0; g < 8; ++g) s += prtB[g][tid - 32];
    rp[blockIdx.x * 32 + (tid - 32)] = (float)s;
  }

  // coalesced wide stores: 2304 uint4 per matrix = 9 per thread
  const uint4* sA = (const uint4*)bufA;
  const uint4* sB = (const uint4*)bufB;
  uint4* gA = (uint4*)(Aext + (size_t)blockIdx.x * 32 * KE);
  uint4* gB = (uint4*)(Bext + (size_t)blockIdx.x * 32 * KE);
#pragma unroll
  for (int it = 0; it < 9; ++it) {
    gA[it * 256 + tid] = sA[it * 256 + tid];
    gB[it * 256 + tid] = sB[it * 256 + tid];
  }
}

// --- MFMA GEMM: round-10 structure, fragment-streaming to kill the spill -----
// LDS tile: 128 rows x 64 halves (8 slots of 16 B), single buffer (32 KB).
// Logical slice s of row r lives at phys slot (s ^ (r & 7)):
//   s in [0,4): hi window octet s;  s in [4,8): lo octet s-4.
// Fragment plan per window: ah[4]+al[4] resident (32 regs); bh_j / bl_j
// streamed one tile at a time (4 regs). Peak unified regs ~ acc(64)+36+addr
// ~= 115 <= 128 -> (256,4) budget fits with NO spill (round 10 spilled ~2KB/
// block at ~132 regs). Same 16 ds_reads, 48 MFMAs, measured-0-conflict
// swizzle. 4 blocks/CU (measured best residency).
__global__ __launch_bounds__(256, 4)
void gemm_argmin_kernel(const f16* __restrict__ A, const f16* __restrict__ B,
                        const float* __restrict__ rq,
                        unsigned long long* __restrict__ best) {
  __shared__ f16 Ash[128 * 64];   // 16 KB
  __shared__ f16 Bsh[128 * 64];   // 16 KB

  const int nBase = blockIdx.x * 128;
  const int mBase = blockIdx.y * 128;
  const f16* Ab = A + (size_t)mBase * KE;   // block-uniform -> SGPR pair
  const f16* Bb = B + (size_t)nBase * KE;
  const int t = threadIdx.x;
  const int w = t >> 6;           // wave 0..3
  const int l = t & 63;

  // ---- staging decode: per issue, 64 lanes cover 8 rows x 8 phys slots ----
  const int lr = l >> 3;                 // row within 8-row issue group
  const int lt = l & 7;                  // phys 16B slot
  const int sl = lt ^ (lr & 7);          // logical slice this lane fetches
  const int sColOff = (sl < 4) ? sl * 8 : KD + (sl & 3) * 8;  // + kw*32/window
  int rowHalf[4];                        // identical for A and B
#pragma unroll
  for (int ig = 0; ig < 4; ++ig)
    rowHalf[ig] = (w * 32 + ig * 8 + lr) * KE + sColOff;

  // ---- fragment decode (16x16x32) ----
  const int m16 = l & 15;
  const int q   = l >> 4;                // k-quad
  const int pHi = q ^ (m16 & 7);         // phys slot of hi octet q
  const int pLo = pHi ^ 4;               // phys slot of lo octet q
  const int wRow = (w & 1) * 64;
  const int wCol = (w >> 1) * 64;
  const int aHiOff = m16 * 64 + pHi * 8; // + (wRow + i*16)*64
  const int aLoOff = m16 * 64 + pLo * 8;

  floatx4 acc[4][4] = {};

#pragma unroll
  for (int kw = 0; kw < NWIN; ++kw) {
    __syncthreads();                     // previous window's reads complete
#pragma unroll
    for (int ig = 0; ig < 4; ++ig)
      __builtin_amdgcn_global_load_lds(AS1(Ab + rowHalf[ig] + kw * 32),
                                       AS3(&Ash[(w * 32 + ig * 8) * 64]), 16, 0, 0);
#pragma unroll
    for (int ig = 0; ig < 4; ++ig)
      __builtin_amdgcn_global_load_lds(AS1(Bb + rowHalf[ig] + kw * 32),
                                       AS3(&Bsh[(w * 32 + ig * 8) * 64]), 16, 0, 0);
    __syncthreads();                     // staging drained (vmcnt0 + barrier)

    // resident A fragments (hi + lo)
    half8 ah[4], al[4];
#pragma unroll
    for (int i = 0; i < 4; ++i) {
      ah[i] = *(const half8*)&Ash[(wRow + i * 16) * 64 + aHiOff];
      al[i] = *(const half8*)&Ash[(wRow + i * 16) * 64 + aLoOff];
    }
    // stream bh_j: hi.hi and lo.hi share it
#pragma unroll
    for (int j = 0; j < 4; ++j) {
      half8 bh = *(const half8*)&Bsh[(wCol + j * 16) * 64 + aHiOff];
#pragma unroll
      for (int i = 0; i < 4; ++i)
        acc[i][j] = __builtin_amdgcn_mfma_f32_16x16x32_f16(ah[i], bh, acc[i][j], 0, 0, 0);
#pragma unroll
      for (int i = 0; i < 4; ++i)
        acc[i][j] = __builtin_amdgcn_mfma_f32_16x16x32_f16(al[i], bh, acc[i][j], 0, 0, 0);
    }
    // stream bl_j: hi.lo
#pragma unroll
    for (int j = 0; j < 4; ++j) {
      half8 bl = *(const half8*)&Bsh[(wCol + j * 16) * 64 + aLoOff];
#pragma unroll
      for (int i = 0; i < 4; ++i)
        acc[i][j] = __builtin_amdgcn_mfma_f32_16x16x32_f16(ah[i], bl, acc[i][j], 0, 0, 0);
    }
  }

  // ---- epilogue: f = rq[col] - 2*dot, packed argmin ----
  // C/D layout (16x16): col = lane&15, row = (lane>>4)*4 + reg
  const int colBase = nBase + wCol + m16;
  float rqv[4];
#pragma unroll
  for (int j = 0; j < 4; ++j) rqv[j] = rq[colBase + j * 16];

#pragma unroll
  for (int i = 0; i < 4; ++i) {
    const int rowB = mBase + wRow + i * 16 + q * 4;
#pragma unroll
    for (int r = 0; r < 4; ++r) {
      unsigned long long pk = 0xFFFFFFFFFFFFFFFFULL;
#pragma unroll
      for (int j = 0; j < 4; ++j) {
        float f = fmaf(-2.0f, acc[i][j][r], rqv[j]);
        unsigned int bits = __float_as_uint(f);
        unsigned int key = (bits & 0x80000000u) ? ~bits : (bits | 0x80000000u);
        unsigned long long cand =
            ((unsigned long long)key << 32) | (unsigned)(colBase + j * 16);
        pk = pk < cand ? pk : cand;
      }
#pragma unroll
      for (int sft = 1; sft < 16; sft <<= 1) {
        unsigned long long o = __shfl_xor(pk, sft, 16);
        pk = pk < o ? pk : o;
      }
      if (m16 == 0) atomicMin(best + rowB + r, pk);
    }
  }
}

// ---------------------------- finalize ---------------------------------------
__global__ void finalize_kernel(const unsigned long long* __restrict__ best,
                                const float* __restrict__ rp,
                                float* __restrict__ out) {
  int i = blockIdx.x * 256 + threadIdx.x;
  if (i >= NPT) return;
  unsigned long long v = best[i];
  unsigned int col = (unsigned int)(v & 0xFFFFFFFFu);
  unsigned int key = (unsigned int)(v >> 32);
  unsigned int bits = (key & 0x80000000u) ? (key & 0x7FFFFFFFu) : ~key;
  float fmin = __uint_as_float(bits);
  out[i]           = (float)(col >> 7);   // idy
  out[NPT + i]     = (float)(col & 127);  // idx
  out[2 * NPT + i] = rp[i] + fmin;        // nnd
}

extern "C" void kernel_launch(void* const* d_in, const int* in_sizes, int n_in,
                              void* d_out, int out_size, void* d_ws, size_t ws_size,
                              hipStream_t stream) {
  const float* src = (const float*)d_in[0];  // source_map (1,32,128,128)
  const float* tgt = (const float*)d_in[1];  // target_map (1,32,128,128)
  float* out = (float*)d_out;

  // workspace layout (bytes):
  //   Aext: [0, 18874368)        16384 x 576 f16 (point-major [hi|lo])
  //   Bext: [18874368, 37748736)
  //   rq  : [37748736, 37814272) 16384 fp32 (source-side norms for the f-term)
  //   rp  : [37814272, 37879808)
  //   best: [37879808, 38010880) 16384 u64 packed (key<<32)|col
  char* ws = (char*)d_ws;
  f16* Aext = (f16*)(ws);
  f16* Bext = (f16*)(ws + 18874368);
  float* rq = (float*)(ws + 37748736);
  float* rp = (float*)(ws + 37814272);
  unsigned long long* best = (unsigned long long*)(ws + 37879808);

  extract_split_kernel<<<NPT / 32, 256, 0, stream>>>(src, tgt, Aext, Bext,
                                                     rq, rp, best);
  {
    dim3 grid(128, 128);
    gemm_argmin_kernel<<<grid, 256, 0, stream>>>(Aext, Bext, rq, best);
  }
  finalize_kernel<<<NPT / 256, 256, 0, stream>>>(best, rp, out);
}

// Round 13
// 540.761 us; speedup vs baseline: 2.7584x; 1.0619x over previous
//
#include <hip/hip_runtime.h>
#include <stdint.h>

// Problem constants (n=1, c=32, h=w=128, p=3)
#define NPT    16384        // points (h*w)
#define KD     288          // c*p*p
#define KE     576          // per-point row: [hi(288) | lo(288)] f16
#define NWIN   9            // 9 merged K-windows of 32 (hi+lo staged together)

typedef _Float16 f16;
typedef __attribute__((ext_vector_type(8))) _Float16 half8;
typedef __attribute__((ext_vector_type(4))) float floatx4;

#define AS1(p) ((const __attribute__((address_space(1))) uint32_t*)(p))
#define AS3(p) ((__attribute__((address_space(3))) uint32_t*)(p))

// -------- patch extraction + fp32->2xf16 split + fused norms/init ------------
__global__ __launch_bounds__(256)
void extract_split_kernel(const float* __restrict__ src,
                          const float* __restrict__ tgt,
                          f16* __restrict__ Aext,
                          f16* __restrict__ Bext,
                          float* __restrict__ rq,
                          float* __restrict__ rp,
                          unsigned long long* __restrict__ best) {
  __shared__ f16 bufA[32 * KE];       // 36 KB
  __shared__ f16 bufB[32 * KE];       // 36 KB
  __shared__ double prtA[8][32];
  __shared__ double prtB[8][32];

  const int tid = threadIdx.x;
  const int p  = tid & 31;            // local point
  const int cg = tid >> 5;            // channel group 0..7
  const int point = blockIdx.x * 32 + p;
  const int y = point >> 7, x = point & 127;

  double sq = 0.0, sp_ = 0.0;
#pragma unroll
  for (int cc = 0; cc < 4; ++cc) {
    const int c = cg * 4 + cc;
#pragma unroll
    for (int dy = 0; dy < 3; ++dy) {
      int yy = y + dy - 1; yy = yy < 0 ? 0 : (yy > 127 ? 127 : yy);
#pragma unroll
      for (int dx = 0; dx < 3; ++dx) {
        int xx = x + dx - 1; xx = xx < 0 ? 0 : (xx > 127 ? 127 : xx);
        const int k = c * 9 + dy * 3 + dx;
        const int m = (c << 14) + (yy << 7) + xx;
        float v = src[m];
        sq += (double)v * (double)v;
        f16 h = (f16)v;
        bufA[p * KE + k] = h;
        bufA[p * KE + KD + k] = (f16)(v - (float)h);
        v = tgt[m];
        sp_ += (double)v * (double)v;
        h = (f16)v;
        bufB[p * KE + k] = h;
        bufB[p * KE + KD + k] = (f16)(v - (float)h);
      }
    }
  }
  prtA[cg][p] = sq;
  prtB[cg][p] = sp_;
  __syncthreads();

  if (tid < 32) {
    double s = 0.0;
#pragma unroll
    for (int g = 0; g < 8; ++g) s += prtA[g][tid];
    rq[blockIdx.x * 32 + tid] = (float)s;
    best[blockIdx.x * 32 + tid] = 0xFFFFFFFFFFFFFFFFULL;
  } else if (tid < 64) {
    double s = 0.0;
#pragma unroll
    for (int g = 0; g < 8; ++g) s += prtB[g][tid - 32];
    rp[blockIdx.x * 32 + (tid - 32)] = (float)s;
  }

  // coalesced wide stores: 2304 uint4 per matrix = 9 per thread
  const uint4* sA = (const uint4*)bufA;
  const uint4* sB = (const uint4*)bufB;
  uint4* gA = (uint4*)(Aext + (size_t)blockIdx.x * 32 * KE);
  uint4* gB = (uint4*)(Bext + (size_t)blockIdx.x * 32 * KE);
#pragma unroll
  for (int it = 0; it < 9; ++it) {
    gA[it * 256 + tid] = sA[it * 256 + tid];
    gB[it * 256 + tid] = sB[it * 256 + tid];
  }
}

// --- MFMA GEMM: round-12 body + XCD-aware supertile swizzle ------------------
// Theory: staging reads 4.7 GB in ~520 us = 9.1 TB/s from cache hierarchy.
// Default dispatch puts ~19 MB of B-tiles in flight per XCD (>> 4 MiB L2),
// so B staging streams from Infinity Cache -> chip-level L3 BW ceiling that
// explains occupancy saturation + all pipes ~43%. Swizzle: 1D grid, 16x8
// supertiles (128 blocks). Blocks round-robin across 8 XCDs, so XCD k gets
// rx==k: ONE B-tile + 16 A-tiles = 2.4 MB < 4 MiB L2. L3 traffic drops ~10x.
__global__ __launch_bounds__(256, 4)
void gemm_argmin_kernel(const f16* __restrict__ A, const f16* __restrict__ B,
                        const float* __restrict__ rq,
                        unsigned long long* __restrict__ best) {
  __shared__ f16 Ash[128 * 64];   // 16 KB
  __shared__ f16 Bsh[128 * 64];   // 16 KB

  // ---- supertile swizzle: L -> (bx, by) ----
  const int L  = blockIdx.x;          // 0..16383
  const int st = L >> 7;              // supertile 0..127 (grid 16 x-major)
  const int r  = L & 127;
  const int bx = ((st & 15) << 3) | (r & 7);    // 0..127
  const int by = ((st >> 4) << 4) | (r >> 3);   // 0..127

  const int nBase = bx * 128;
  const int mBase = by * 128;
  const f16* Ab = A + (size_t)mBase * KE;   // block-uniform -> SGPR pair
  const f16* Bb = B + (size_t)nBase * KE;
  const int t = threadIdx.x;
  const int w = t >> 6;           // wave 0..3
  const int l = t & 63;

  // ---- staging decode: per issue, 64 lanes cover 8 rows x 8 phys slots ----
  const int lr = l >> 3;                 // row within 8-row issue group
  const int lt = l & 7;                  // phys 16B slot
  const int sl = lt ^ (lr & 7);          // logical slice this lane fetches
  const int sColOff = (sl < 4) ? sl * 8 : KD + (sl & 3) * 8;  // + kw*32/window
  int rowHalf[4];                        // identical for A and B
#pragma unroll
  for (int ig = 0; ig < 4; ++ig)
    rowHalf[ig] = (w * 32 + ig * 8 + lr) * KE + sColOff;

  // ---- fragment decode (16x16x32) ----
  const int m16 = l & 15;
  const int q   = l >> 4;                // k-quad
  const int pHi = q ^ (m16 & 7);         // phys slot of hi octet q
  const int pLo = pHi ^ 4;               // phys slot of lo octet q
  const int wRow = (w & 1) * 64;
  const int wCol = (w >> 1) * 64;
  const int aHiOff = m16 * 64 + pHi * 8; // + (wRow + i*16)*64
  const int aLoOff = m16 * 64 + pLo * 8;

  floatx4 acc[4][4] = {};

#pragma unroll
  for (int kw = 0; kw < NWIN; ++kw) {
    __syncthreads();                     // previous window's reads complete
#pragma unroll
    for (int ig = 0; ig < 4; ++ig)
      __builtin_amdgcn_global_load_lds(AS1(Ab + rowHalf[ig] + kw * 32),
                                       AS3(&Ash[(w * 32 + ig * 8) * 64]), 16, 0, 0);
#pragma unroll
    for (int ig = 0; ig < 4; ++ig)
      __builtin_amdgcn_global_load_lds(AS1(Bb + rowHalf[ig] + kw * 32),
                                       AS3(&Bsh[(w * 32 + ig * 8) * 64]), 16, 0, 0);
    __syncthreads();                     // staging drained (vmcnt0 + barrier)

    // resident A fragments (hi + lo); stream B fragments one tile at a time
    half8 ah[4], al[4];
#pragma unroll
    for (int i = 0; i < 4; ++i) {
      ah[i] = *(const half8*)&Ash[(wRow + i * 16) * 64 + aHiOff];
      al[i] = *(const half8*)&Ash[(wRow + i * 16) * 64 + aLoOff];
    }
#pragma unroll
    for (int j = 0; j < 4; ++j) {
      half8 bh = *(const half8*)&Bsh[(wCol + j * 16) * 64 + aHiOff];
#pragma unroll
      for (int i = 0; i < 4; ++i)
        acc[i][j] = __builtin_amdgcn_mfma_f32_16x16x32_f16(ah[i], bh, acc[i][j], 0, 0, 0);
#pragma unroll
      for (int i = 0; i < 4; ++i)
        acc[i][j] = __builtin_amdgcn_mfma_f32_16x16x32_f16(al[i], bh, acc[i][j], 0, 0, 0);
    }
#pragma unroll
    for (int j = 0; j < 4; ++j) {
      half8 bl = *(const half8*)&Bsh[(wCol + j * 16) * 64 + aLoOff];
#pragma unroll
      for (int i = 0; i < 4; ++i)
        acc[i][j] = __builtin_amdgcn_mfma_f32_16x16x32_f16(ah[i], bl, acc[i][j], 0, 0, 0);
    }
  }

  // ---- epilogue: f = rq[col] - 2*dot, packed argmin ----
  // C/D layout (16x16): col = lane&15, row = (lane>>4)*4 + reg
  const int colBase = nBase + wCol + m16;
  float rqv[4];
#pragma unroll
  for (int j = 0; j < 4; ++j) rqv[j] = rq[colBase + j * 16];

#pragma unroll
  for (int i = 0; i < 4; ++i) {
    const int rowB = mBase + wRow + i * 16 + q * 4;
#pragma unroll
    for (int r2 = 0; r2 < 4; ++r2) {
      unsigned long long pk = 0xFFFFFFFFFFFFFFFFULL;
#pragma unroll
      for (int j = 0; j < 4; ++j) {
        float f = fmaf(-2.0f, acc[i][j][r2], rqv[j]);
        unsigned int bits = __float_as_uint(f);
        unsigned int key = (bits & 0x80000000u) ? ~bits : (bits | 0x80000000u);
        unsigned long long cand =
            ((unsigned long long)key << 32) | (unsigned)(colBase + j * 16);
        pk = pk < cand ? pk : cand;
      }
#pragma unroll
      for (int sft = 1; sft < 16; sft <<= 1) {
        unsigned long long o = __shfl_xor(pk, sft, 16);
        pk = pk < o ? pk : o;
      }
      if (m16 == 0) atomicMin(best + rowB + r2, pk);
    }
  }
}

// ---------------------------- finalize ---------------------------------------
__global__ void finalize_kernel(const unsigned long long* __restrict__ best,
                                const float* __restrict__ rp,
                                float* __restrict__ out) {
  int i = blockIdx.x * 256 + threadIdx.x;
  if (i >= NPT) return;
  unsigned long long v = best[i];
  unsigned int col = (unsigned int)(v & 0xFFFFFFFFu);
  unsigned int key = (unsigned int)(v >> 32);
  unsigned int bits = (key & 0x80000000u) ? (key & 0x7FFFFFFFu) : ~key;
  float fmin = __uint_as_float(bits);
  out[i]           = (float)(col >> 7);   // idy
  out[NPT + i]     = (float)(col & 127);  // idx
  out[2 * NPT + i] = rp[i] + fmin;        // nnd
}

extern "C" void kernel_launch(void* const* d_in, const int* in_sizes, int n_in,
                              void* d_out, int out_size, void* d_ws, size_t ws_size,
                              hipStream_t stream) {
  const float* src = (const float*)d_in[0];  // source_map (1,32,128,128)
  const float* tgt = (const float*)d_in[1];  // target_map (1,32,128,128)
  float* out = (float*)d_out;

  // workspace layout (bytes):
  //   Aext: [0, 18874368)        16384 x 576 f16 (point-major [hi|lo])
  //   Bext: [18874368, 37748736)
  //   rq  : [37748736, 37814272) 16384 fp32
  //   rp  : [37814272, 37879808)
  //   best: [37879808, 38010880) 16384 u64 packed (key<<32)|col
  char* ws = (char*)d_ws;
  f16* Aext = (f16*)(ws);
  f16* Bext = (f16*)(ws + 18874368);
  float* rq = (float*)(ws + 37748736);
  float* rp = (float*)(ws + 37814272);
  unsigned long long* best = (unsigned long long*)(ws + 37879808);

  extract_split_kernel<<<NPT / 32, 256, 0, stream>>>(src, tgt, Aext, Bext,
                                                     rq, rp, best);
  gemm_argmin_kernel<<<16384, 256, 0, stream>>>(Aext, Bext, rq, best);
  finalize_kernel<<<NPT / 256, 256, 0, stream>>>(best, rp, out);
}